// Round 8
// baseline (2090.807 us; speedup 1.0000x reference)
//
#include <hip/hip_runtime.h>
#include <cmath>

typedef unsigned int uint32;
typedef _Float16 v2h __attribute__((ext_vector_type(2)));

__device__ __forceinline__ float fast_tanh(float x) {
    // tanh(x) = 1 - 2/(exp(2x)+1); correct saturation for large |x|
    float e = __expf(2.0f * x);
    return 1.0f - 2.0f * __builtin_amdgcn_rcpf(e + 1.0f);
}

__device__ __forceinline__ uint32 pkf(float x, float y) {
    v2h v; v.x = (_Float16)x; v.y = (_Float16)y;
    return __builtin_bit_cast(uint32, v);
}
__device__ __forceinline__ v2h bch(uint32 u) { return __builtin_bit_cast(v2h, u); }

__device__ __forceinline__ float dot2(v2h a, v2h b, float c) {
#if __has_builtin(__builtin_amdgcn_fdot2)
    return __builtin_amdgcn_fdot2(a, b, c, false);   // v_dot2_f32_f16, fp32 accum
#else
    return fmaf((float)a[0], (float)b[0], fmaf((float)a[1], (float)b[1], c));
#endif
}

template <int CTRL>
__device__ __forceinline__ float dpp_radd(float x) {
    int t = __builtin_amdgcn_update_dpp(0, __builtin_bit_cast(int, x),
                                        CTRL, 0xf, 0xf, true);
    return x + __builtin_bit_cast(float, t);
}
// Full wave64 sum -> lane 63, broadcast via readlane (uniform SGPR).
__device__ __forceinline__ float wave_sum_bcast(float x) {
    x = dpp_radd<0x111>(x);   // row_shr:1
    x = dpp_radd<0x112>(x);   // row_shr:2
    x = dpp_radd<0x114>(x);   // row_shr:4
    x = dpp_radd<0x118>(x);   // row_shr:8
    x = dpp_radd<0x142>(x);   // row_bcast:15
    x = dpp_radd<0x143>(x);   // row_bcast:31
    int s = __builtin_amdgcn_readlane(__builtin_bit_cast(int, x), 63);
    return __builtin_bit_cast(float, s);
}

// ---- kernel 1: counting sort of rows by integration length (descending) ----
// perm[rank] = row, rank 0 = longest. Pairing (2k,2k+1) then matches lengths.
__global__ void pair_sort_kernel(const int* __restrict__ length,
                                 int* __restrict__ perm, int B) {
    __shared__ int bins[128];
    const int tid = threadIdx.x;   // 256 threads
    if (tid < 128) bins[tid] = 0;
    __syncthreads();
    for (int r = tid; r < B; r += 256) {
        int len = length[r] - 1;
        len = min(max(len, 0), 127);
        atomicAdd(&bins[len], 1);
    }
    __syncthreads();
    if (tid == 0) {                 // suffix sum: start of each bin, descending
        int acc = 0;
        for (int k = 127; k >= 0; --k) { int c = bins[k]; bins[k] = acc; acc += c; }
    }
    __syncthreads();
    for (int r = tid; r < B; r += 256) {
        int len = length[r] - 1;
        len = min(max(len, 0), 127);
        int rank = atomicAdd(&bins[len], 1);
        perm[rank] = r;
    }
}

// ---- kernel 2: one wave integrates TWO length-matched rows (ILP fills the
// latency bubbles that 1-row/wave left exposed; weights are batch-shared so
// register cost barely grows). Per-row dataflow identical to the R4 kernel.
__global__ __launch_bounds__(64, 1) void node_kernel(
    const float* __restrict__ y0,        // [B]
    const float* __restrict__ latent,    // [B,32]
    const int*   __restrict__ length,    // [B]
    const float* __restrict__ dense_cs,  // [B,D]
    const float* __restrict__ W1,        // [128,43]
    const float* __restrict__ b1,        // [128]
    const float* __restrict__ W2,        // [128,128]
    const float* __restrict__ b2,        // [128]
    const float* __restrict__ W3,        // [41,128]
    const float* __restrict__ b3,        // [41]
    const int*   __restrict__ perm,      // [B] sorted row indices
    float* __restrict__ out,             // [B,T]
    int T, int D)
{
    const int lane = threadIdx.x;        // 0..63
    const int blk  = blockIdx.x;
    const int u0 = lane * 2, u1 = u0 + 1;

    const int rowi[2] = { perm[2 * blk], perm[2 * blk + 1] };

    __shared__ __align__(16) uint32 s_h1[2][64];
    __shared__ __align__(16) float  s_cs[2][256];

    // stage both rows' concentration series
#pragma unroll
    for (int r = 0; r < 2; ++r) {
        if (D == 256) {
            reinterpret_cast<float4*>(s_cs[r])[lane] =
                reinterpret_cast<const float4*>(dense_cs + rowi[r] * D)[lane];
        } else {
            for (int q = lane; q < D; q += 64) s_cs[r][q] = dense_cs[rowi[r] * D + q];
        }
    }

    // ---- W2 rows u0,u1 -> packed fp16 (shared by both rows) ----
    uint32 w2a[64], w2b[64];
    {
        const float2* r0 = reinterpret_cast<const float2*>(W2 + u0 * 128);
        const float2* r1 = reinterpret_cast<const float2*>(W2 + u1 * 128);
#pragma unroll
        for (int k = 0; k < 64; ++k) {
            float2 f0 = r0[k], f1 = r1[k];
            w2a[k] = pkf(f0.x, f0.y);
            w2b[k] = pkf(f1.x, f1.y);
        }
    }
#pragma unroll
    for (int k = 0; k < 64; ++k) {
        asm volatile("" : "+v"(w2a[k]));
        asm volatile("" : "+v"(w2b[k]));
    }

    // ---- W1 rows (shared), per-row layer-1 constants ----
    const float* W1r0 = W1 + u0 * 43;
    const float* W1r1 = W1 + u1 * 43;
    float w1a[11], w1b[11];
#pragma unroll
    for (int d = 0; d < 9; ++d) { w1a[d] = W1r0[d]; w1b[d] = W1r1[d]; }
    w1a[9] = W1r0[41]; w1a[10] = W1r0[42];
    w1b[9] = W1r1[41]; w1b[10] = W1r1[42];

    float c1a[2], c1b[2];
#pragma unroll
    for (int r = 0; r < 2; ++r) {
        const float* lat = latent + rowi[r] * 32;
        float ca = b1[u0], cb = b1[u1];
#pragma unroll
        for (int l = 0; l < 32; ++l) {
            float lv = lat[l];
            ca = fmaf(W1r0[9 + l], lv, ca);
            cb = fmaf(W1r1[9 + l], lv, cb);
        }
        c1a[r] = ca; c1b[r] = cb;
    }
    const float b2a = b2[u0], b2b = b2[u1];

    // ---- W3 columns (shared), biases ----
    uint32 w3p[9]; float b3r[9];
#pragma unroll
    for (int i = 0; i < 9; ++i) {
        w3p[i] = pkf(W3[i * 128 + u0], W3[i * 128 + u1]);
        b3r[i] = b3[i];
        asm volatile("" : "+v"(w3p[i]));
    }
#pragma unroll
    for (int d = 0; d < 11; ++d) {
        asm volatile("" : "+v"(w1a[d]));
        asm volatile("" : "+v"(w1b[d]));
    }

    // ---- per-row RK4 state (wave-uniform, registers) ----
    float Y[2][9], K[2][9], Ys[2][9], tend[2];
#pragma unroll
    for (int r = 0; r < 2; ++r) {
        const float yv = y0[rowi[r]];
#pragma unroll
        for (int i = 0; i < 9; ++i) { Y[r][i] = (i == 0) ? yv : 0.0f; Ys[r][i] = Y[r][i]; K[r][i] = 0.0f; }
        int len = length[rowi[r]] - 1;
        if (len < 0) len = 0;
        tend[r] = (float)len;
        if (lane == 0) out[rowi[r] * T] = yv;
    }
    __syncthreads();   // covers s_cs staging

    const int nsub = (T - 1) * 2;
    for (int step = 0; step < nsub; ++step) {
        const float t0 = 0.5f * (float)step;   // exact

        // both rows dead -> fill tails, done (pairing makes this late & matched)
        if (t0 > tend[0] && t0 > tend[1]) {
            const int base = (step >> 1) + 1;
            for (int i = base + lane; i < T; i += 64) {
                out[rowi[0] * T + i] = Y[0][0];
                out[rowi[1] * T + i] = Y[1][0];
            }
            break;
        }

        // concentration at the 3 distinct stage times, per row
        float cv[2][3];
#pragma unroll
        for (int r = 0; r < 2; ++r) {
#pragma unroll
            for (int m = 0; m < 3; ++m) {
                const float tau = t0 + 0.25f * (float)m;
                int ii = (int)tau;
                int idx = ii + ((tau - (float)ii) > 0.0f ? 1 : 0);
                idx = min(max(idx, 1), D - 1);
                float w = tau - (float)(idx - 1);
                w = fminf(fmaxf(w, 0.0f), 1.0f);
                cv[r][m] = (1.0f - w) * s_cs[r][idx - 1] + w * s_cs[r][idx];
            }
        }

#pragma unroll
        for (int s = 0; s < 4; ++s) {
            const float tau = t0 + ((s == 0) ? 0.0f : (s == 3) ? 0.5f : 0.25f);
            const int cm = (s == 0) ? 0 : (s == 3) ? 2 : 1;

            // ---- layer 1, both rows (independent chains) ----
#pragma unroll
            for (int r = 0; r < 2; ++r) {
                const float c = cv[r][cm];
                float pa = fmaf(w1a[9], tau, c1a[r]); pa = fmaf(w1a[10], c, pa);
                float pb = fmaf(w1b[9], tau, c1b[r]); pb = fmaf(w1b[10], c, pb);
#pragma unroll
                for (int d = 0; d < 9; ++d) {
                    pa = fmaf(w1a[d], Ys[r][d], pa);
                    pb = fmaf(w1b[d], Ys[r][d], pb);
                }
                s_h1[r][lane] = pkf(fast_tanh(pa), fast_tanh(pb));
            }
            // single-wave workgroup: drain LDS, no barrier
            asm volatile("s_waitcnt lgkmcnt(0)" ::: "memory");

            // ---- layer 2, both rows: 8 fp32 chains per row over shared W2 ----
            float accA[2][4], accB[2][4];   // [row][chain] for units u0,u1
#pragma unroll
            for (int r = 0; r < 2; ++r)
#pragma unroll
                for (int q = 0; q < 4; ++q) { accA[r][q] = 0.f; accB[r][q] = 0.f; }

#pragma unroll
            for (int half = 0; half < 2; ++half) {
                uint4 hb[2][8];
#pragma unroll
                for (int r = 0; r < 2; ++r) {
                    const uint4* s4 = reinterpret_cast<const uint4*>(s_h1[r]);
#pragma unroll
                    for (int q = 0; q < 8; ++q) hb[r][q] = s4[8 * half + q];
                }
#pragma unroll
                for (int q = 0; q < 8; ++q) {
                    const int k = 32 * half + 4 * q;
#pragma unroll
                    for (int r = 0; r < 2; ++r) {
                        accA[r][2 * half + 0] = dot2(bch(w2a[k + 0]), bch(hb[r][q].x), accA[r][2 * half + 0]);
                        accA[r][2 * half + 1] = dot2(bch(w2a[k + 1]), bch(hb[r][q].y), accA[r][2 * half + 1]);
                        accA[r][2 * half + 0] = dot2(bch(w2a[k + 2]), bch(hb[r][q].z), accA[r][2 * half + 0]);
                        accA[r][2 * half + 1] = dot2(bch(w2a[k + 3]), bch(hb[r][q].w), accA[r][2 * half + 1]);
                        accB[r][2 * half + 0] = dot2(bch(w2b[k + 0]), bch(hb[r][q].x), accB[r][2 * half + 0]);
                        accB[r][2 * half + 1] = dot2(bch(w2b[k + 1]), bch(hb[r][q].y), accB[r][2 * half + 1]);
                        accB[r][2 * half + 0] = dot2(bch(w2b[k + 2]), bch(hb[r][q].z), accB[r][2 * half + 0]);
                        accB[r][2 * half + 1] = dot2(bch(w2b[k + 3]), bch(hb[r][q].w), accB[r][2 * half + 1]);
                    }
                }
            }

            uint32 h2p[2];
#pragma unroll
            for (int r = 0; r < 2; ++r) {
                const float h2a = fast_tanh((accA[r][0] + accA[r][1]) + (accA[r][2] + accA[r][3]) + b2a);
                const float h2b = fast_tanh((accB[r][0] + accB[r][1]) + (accB[r][2] + accB[r][3]) + b2b);
                h2p[r] = pkf(h2a, h2b);
            }

            // ---- layer 3: 18 independent DPP reductions (interleaved) ----
            float p[18];
#pragma unroll
            for (int r = 0; r < 2; ++r)
#pragma unroll
                for (int i = 0; i < 9; ++i)
                    p[9 * r + i] = dot2(bch(w3p[i]), bch(h2p[r]), 0.0f);
#pragma unroll
            for (int i = 0; i < 18; ++i) p[i] = wave_sum_bcast(p[i]);

            // ---- vf finalize + RK4, both rows ----
#pragma unroll
            for (int r = 0; r < 2; ++r) {
                const float alive = (tau <= tend[r]) ? 1.0f : 0.0f;
                float kk[9];
                kk[0] = alive * (-__cosf(p[9 * r] + b3r[0]));
#pragma unroll
                for (int i = 1; i < 9; ++i) kk[i] = alive * (p[9 * r + i] + b3r[i]);

                if (s == 0) {
#pragma unroll
                    for (int i = 0; i < 9; ++i) { K[r][i] = kk[i]; Ys[r][i] = fmaf(0.25f, kk[i], Y[r][i]); }
                } else if (s == 1) {
#pragma unroll
                    for (int i = 0; i < 9; ++i) { K[r][i] = fmaf(2.0f, kk[i], K[r][i]); Ys[r][i] = fmaf(0.25f, kk[i], Y[r][i]); }
                } else if (s == 2) {
#pragma unroll
                    for (int i = 0; i < 9; ++i) { K[r][i] = fmaf(2.0f, kk[i], K[r][i]); Ys[r][i] = fmaf(0.5f, kk[i], Y[r][i]); }
                } else {
#pragma unroll
                    for (int i = 0; i < 9; ++i) {
                        K[r][i] = K[r][i] + kk[i];
                        Y[r][i] = fmaf(1.0f / 12.0f, K[r][i], Y[r][i]);  // dt/6
                        Ys[r][i] = Y[r][i];
                    }
                    if (lane == 0 && (step & 1))
                        out[rowi[r] * T + (step >> 1) + 1] = Y[r][0];
                }
            }
        }
    }
}

extern "C" void kernel_launch(void* const* d_in, const int* in_sizes, int n_in,
                              void* d_out, int out_size, void* d_ws, size_t ws_size,
                              hipStream_t stream) {
    // setup_inputs order:
    // 0 ts[T] 1 y0[B] 2 latent[B,32] 3 length[B] 4 dense_ts[D] 5 dense_cs[B,D]
    // 6 W1 7 b1 8 W2 9 b2 10 W3 11 b3
    const float* y0       = (const float*)d_in[1];
    const float* latent   = (const float*)d_in[2];
    const int*   length   = (const int*)  d_in[3];
    const float* dense_cs = (const float*)d_in[5];
    const float* W1 = (const float*)d_in[6];
    const float* b1 = (const float*)d_in[7];
    const float* W2 = (const float*)d_in[8];
    const float* b2 = (const float*)d_in[9];
    const float* W3 = (const float*)d_in[10];
    const float* b3 = (const float*)d_in[11];
    float* out = (float*)d_out;

    const int T = in_sizes[0];   // 128
    const int B = in_sizes[1];   // 1024
    const int D = in_sizes[4];   // 256

    int* perm = (int*)d_ws;      // [B]

    pair_sort_kernel<<<1, 256, 0, stream>>>(length, perm, B);
    node_kernel<<<B / 2, 64, 0, stream>>>(y0, latent, length, dense_cs,
                                          W1, b1, W2, b2, W3, b3, perm, out, T, D);
}

// Round 9
// 855.816 us; speedup vs baseline: 2.4431x; 2.4431x over previous
//
#include <hip/hip_runtime.h>
#include <cmath>

typedef unsigned int uint32;
typedef _Float16 v2h __attribute__((ext_vector_type(2)));
typedef _Float16 half8 __attribute__((ext_vector_type(8)));
typedef float v4f __attribute__((ext_vector_type(4)));

__device__ __forceinline__ float fast_tanh(float x) {
    // tanh(x) = 1 - 2/(exp(2x)+1); correct saturation for large |x|
    float e = __expf(2.0f * x);
    return 1.0f - 2.0f * __builtin_amdgcn_rcpf(e + 1.0f);
}

__device__ __forceinline__ uint32 pkf(float x, float y) {
    v2h v; v.x = (_Float16)x; v.y = (_Float16)y;
    return __builtin_bit_cast(uint32, v);
}
__device__ __forceinline__ half8 h8(uint4 u) { return __builtin_bit_cast(half8, u); }

// One wave (64 lanes) integrates one batch row.
// Layer 2 (128x128 GEMV) and layer 3 (9x128 GEMV) run on the MATRIX pipe:
//   - W2 preloaded as 8 M-tiles x 4 K-chunks of 16x16x32 f16 A-fragments
//     (A[m=lane&15][k=32q+(lane>>4)*8+j]); resident in AGPR/VGPR.
//   - B-fragment columns are all identical (broadcast h), so any C column is
//     the result: C/D row = (lane>>4)*4+reg (verified layout, guide §3).
//   - Layer-3 bias rides in the MFMA C operand; 9 readlanes broadcast the
//     result to all lanes (replaces the 54-instruction DPP tree).
__global__ __launch_bounds__(64, 1) void node_kernel(
    const float* __restrict__ y0,        // [B]
    const float* __restrict__ latent,    // [B,32]
    const int*   __restrict__ length,    // [B]
    const float* __restrict__ dense_cs,  // [B,D]
    const float* __restrict__ W1,        // [128,43]
    const float* __restrict__ b1,        // [128]
    const float* __restrict__ W2,        // [128,128]
    const float* __restrict__ b2,        // [128]
    const float* __restrict__ W3,        // [41,128]
    const float* __restrict__ b3,        // [41]
    float* __restrict__ out,             // [B,T]
    int T, int D)
{
    const int lane = threadIdx.x;        // 0..63
    const int row  = blockIdx.x;
    const int m16  = lane & 15;          // MFMA m/n index
    const int quad = lane >> 4;          // MFMA k-group
    const int u0 = lane * 2, u1 = u0 + 1;

    __shared__ __align__(16) uint32 s_h1[64];     // h1 as 128 f16 (pair/lane)
    __shared__ __align__(16) float  s_h2pre[128]; // layer-2 pre-activations
    __shared__ __align__(16) uint32 s_h2[64];     // h2 as 128 f16 (pair/lane)
    __shared__ __align__(16) float  s_cs[256];    // concentration series

    // stage dense_cs
    if (D == 256) {
        reinterpret_cast<float4*>(s_cs)[lane] =
            reinterpret_cast<const float4*>(dense_cs + row * D)[lane];
    } else {
        for (int q = lane; q < D; q += 64) s_cs[q] = dense_cs[row * D + q];
    }

    // ---- W2 -> 32 A-fragments (tile t: rows 16t..16t+15; chunk q: k 32q..) ----
    half8 w2f[8][4];
#pragma unroll
    for (int t = 0; t < 8; ++t) {
#pragma unroll
        for (int q = 0; q < 4; ++q) {
            const float* p = W2 + (16 * t + m16) * 128 + 32 * q + quad * 8;
            float4 f0 = *reinterpret_cast<const float4*>(p);
            float4 f1 = *reinterpret_cast<const float4*>(p + 4);
            uint4 u;
            u.x = pkf(f0.x, f0.y); u.y = pkf(f0.z, f0.w);
            u.z = pkf(f1.x, f1.y); u.w = pkf(f1.z, f1.w);
            w2f[t][q] = h8(u);
        }
    }
#pragma unroll
    for (int t = 0; t < 8; ++t)
#pragma unroll
        for (int q = 0; q < 4; ++q)
            asm volatile("" : "+v"(w2f[t][q]));   // keep resident; MFMA reads AGPR/VGPR

    // ---- W3 (padded to 16 rows) -> 4 A-fragments; b3 -> C-fragment ----
    half8 w3f[4];
#pragma unroll
    for (int q = 0; q < 4; ++q) {
        uint4 u; float vals[8];
#pragma unroll
        for (int j = 0; j < 8; ++j) {
            const int k = 32 * q + quad * 8 + j;
            vals[j] = (m16 < 9) ? W3[m16 * 128 + k] : 0.0f;
        }
        u.x = pkf(vals[0], vals[1]); u.y = pkf(vals[2], vals[3]);
        u.z = pkf(vals[4], vals[5]); u.w = pkf(vals[6], vals[7]);
        w3f[q] = h8(u);
    }
#pragma unroll
    for (int q = 0; q < 4; ++q) asm volatile("" : "+v"(w3f[q]));

    v4f c3frag;
#pragma unroll
    for (int r = 0; r < 4; ++r) {
        const int i = quad * 4 + r;
        c3frag[r] = (i < 9) ? b3[i] : 0.0f;
    }

    // ---- W1 rows u0,u1 (state cols + t + c) + layer-1 constants ----
    const float* W1r0 = W1 + u0 * 43;
    const float* W1r1 = W1 + u1 * 43;
    float w1a[11], w1b[11];
#pragma unroll
    for (int d = 0; d < 9; ++d) { w1a[d] = W1r0[d]; w1b[d] = W1r1[d]; }
    w1a[9] = W1r0[41]; w1a[10] = W1r0[42];
    w1b[9] = W1r1[41]; w1b[10] = W1r1[42];

    const float* lat = latent + row * 32;
    float c1a = b1[u0], c1b = b1[u1];
#pragma unroll
    for (int l = 0; l < 32; ++l) {
        float lv = lat[l];
        c1a = fmaf(W1r0[9 + l], lv, c1a);
        c1b = fmaf(W1r1[9 + l], lv, c1b);
    }
    const float b2a = b2[u0], b2b = b2[u1];
#pragma unroll
    for (int d = 0; d < 11; ++d) {
        asm volatile("" : "+v"(w1a[d]));
        asm volatile("" : "+v"(w1b[d]));
    }

    // ---- RK4 state, uniform in every lane ----
    const float y00 = y0[row];
    float Y[9], K[9], Ys[9];
#pragma unroll
    for (int i = 0; i < 9; ++i) { Y[i] = (i == 0) ? y00 : 0.0f; Ys[i] = Y[i]; K[i] = 0.0f; }

    int len = length[row] - 1;
    if (len < 0) len = 0;
    const float tend = (float)len;       // ts = arange
    if (lane == 0) out[row * T] = y00;
    __syncthreads();                     // covers s_cs staging

    const v4f zero4 = {0.0f, 0.0f, 0.0f, 0.0f};

    const int nsub = (T - 1) * 2;
    for (int step = 0; step < nsub; ++step) {
        const float t0 = 0.5f * (float)step;   // exact

        // ---- dead-row fast path (wave-uniform) ----
        if (t0 > tend) {
            const float yv = Y[0];
            for (int i = (step >> 1) + 1 + lane; i < T; i += 64)
                out[row * T + i] = yv;
            break;
        }

        // ---- concentration at the 3 distinct stage times ----
        float cv0, cv1, cv2;
        {
            float tmp[3];
#pragma unroll
            for (int m = 0; m < 3; ++m) {
                const float tau = t0 + 0.25f * (float)m;
                int ii = (int)tau;
                int idx = ii + ((tau - (float)ii) > 0.0f ? 1 : 0);
                idx = min(max(idx, 1), D - 1);
                float w = tau - (float)(idx - 1);
                w = fminf(fmaxf(w, 0.0f), 1.0f);
                tmp[m] = (1.0f - w) * s_cs[idx - 1] + w * s_cs[idx];
            }
            cv0 = tmp[0]; cv1 = tmp[1]; cv2 = tmp[2];
        }

#pragma unroll
        for (int s = 0; s < 4; ++s) {
            const float tau = t0 + ((s == 0) ? 0.0f : (s == 3) ? 0.5f : 0.25f);
            const float c   = (s == 0) ? cv0 : ((s == 3) ? cv2 : cv1);

            // ---- layer 1 (VALU): this lane's two hidden units ----
            float pa = fmaf(w1a[9], tau, c1a); pa = fmaf(w1a[10], c, pa);
            float pb = fmaf(w1b[9], tau, c1b); pb = fmaf(w1b[10], c, pb);
#pragma unroll
            for (int d = 0; d < 9; ++d) {
                pa = fmaf(w1a[d], Ys[d], pa);
                pb = fmaf(w1b[d], Ys[d], pb);
            }
            s_h1[lane] = pkf(fast_tanh(pa), fast_tanh(pb));
            asm volatile("s_waitcnt lgkmcnt(0)" ::: "memory");

            // ---- B-fragments for layer 2: broadcast reads (cols identical) ----
            uint4 b1f[4];
#pragma unroll
            for (int q = 0; q < 4; ++q)
                b1f[q] = reinterpret_cast<const uint4*>(s_h1)[4 * q + quad];

            // ---- layer 2 on the matrix pipe: 8 tiles x 4 K-chunks ----
            v4f acc[8];
#pragma unroll
            for (int t = 0; t < 8; ++t) {
                v4f a = __builtin_amdgcn_mfma_f32_16x16x32_f16(w2f[t][0], h8(b1f[0]), zero4, 0, 0, 0);
                a = __builtin_amdgcn_mfma_f32_16x16x32_f16(w2f[t][1], h8(b1f[1]), a, 0, 0, 0);
                a = __builtin_amdgcn_mfma_f32_16x16x32_f16(w2f[t][2], h8(b1f[2]), a, 0, 0, 0);
                acc[t] = __builtin_amdgcn_mfma_f32_16x16x32_f16(w2f[t][3], h8(b1f[3]), a, 0, 0, 0);
            }

            // ---- compact C-layout -> linear (col-0 lanes write h2pre) ----
            if ((lane & 15) == 0) {
#pragma unroll
                for (int t = 0; t < 8; ++t)
                    reinterpret_cast<v4f*>(s_h2pre)[4 * t + quad] = acc[t];
            }
            asm volatile("s_waitcnt lgkmcnt(0)" ::: "memory");

            // ---- bias + tanh (2/lane), repack to f16 pairs ----
            const float2 hp = reinterpret_cast<const float2*>(s_h2pre)[lane];
            const float h2a = fast_tanh(hp.x + b2a);
            const float h2b = fast_tanh(hp.y + b2b);
            s_h2[lane] = pkf(h2a, h2b);
            asm volatile("s_waitcnt lgkmcnt(0)" ::: "memory");

            // ---- layer 3 on the matrix pipe: 1 tile x 4 K-chunks, bias in C ----
            uint4 b2f[4];
#pragma unroll
            for (int q = 0; q < 4; ++q)
                b2f[q] = reinterpret_cast<const uint4*>(s_h2)[4 * q + quad];
            v4f a3 = __builtin_amdgcn_mfma_f32_16x16x32_f16(w3f[0], h8(b2f[0]), c3frag, 0, 0, 0);
            a3 = __builtin_amdgcn_mfma_f32_16x16x32_f16(w3f[1], h8(b2f[1]), a3, 0, 0, 0);
            a3 = __builtin_amdgcn_mfma_f32_16x16x32_f16(w3f[2], h8(b2f[2]), a3, 0, 0, 0);
            a3 = __builtin_amdgcn_mfma_f32_16x16x32_f16(w3f[3], h8(b2f[3]), a3, 0, 0, 0);

            // ---- broadcast the 9 outputs to all lanes (row=(lane>>4)*4+reg) ----
            float p[9];
#pragma unroll
            for (int i = 0; i < 9; ++i) {
                const int src = (i >> 2) * 16;         // col 0 of the owning quad
                int b = __builtin_amdgcn_readlane(
                            __builtin_bit_cast(int, a3[i & 3]), src);
                p[i] = __builtin_bit_cast(float, b);
            }

            // ---- vf finalize + RK4, uniform in every lane ----
            const float alive = (tau <= tend) ? 1.0f : 0.0f;
            float kk[9];
            kk[0] = alive * (-__cosf(p[0]));
#pragma unroll
            for (int i = 1; i < 9; ++i) kk[i] = alive * p[i];

            if (s == 0) {
#pragma unroll
                for (int i = 0; i < 9; ++i) { K[i] = kk[i]; Ys[i] = fmaf(0.25f, kk[i], Y[i]); }
            } else if (s == 1) {
#pragma unroll
                for (int i = 0; i < 9; ++i) { K[i] = fmaf(2.0f, kk[i], K[i]); Ys[i] = fmaf(0.25f, kk[i], Y[i]); }
            } else if (s == 2) {
#pragma unroll
                for (int i = 0; i < 9; ++i) { K[i] = fmaf(2.0f, kk[i], K[i]); Ys[i] = fmaf(0.5f, kk[i], Y[i]); }
            } else {
#pragma unroll
                for (int i = 0; i < 9; ++i) {
                    K[i] = K[i] + kk[i];
                    Y[i] = fmaf(1.0f / 12.0f, K[i], Y[i]);  // dt/6 = 0.5/6
                    Ys[i] = Y[i];
                }
                if (lane == 0 && (step & 1)) out[row * T + (step >> 1) + 1] = Y[0];
            }
        }
    }
}

extern "C" void kernel_launch(void* const* d_in, const int* in_sizes, int n_in,
                              void* d_out, int out_size, void* d_ws, size_t ws_size,
                              hipStream_t stream) {
    // setup_inputs order:
    // 0 ts[T] 1 y0[B] 2 latent[B,32] 3 length[B] 4 dense_ts[D] 5 dense_cs[B,D]
    // 6 W1 7 b1 8 W2 9 b2 10 W3 11 b3
    const float* y0       = (const float*)d_in[1];
    const float* latent   = (const float*)d_in[2];
    const int*   length   = (const int*)  d_in[3];
    const float* dense_cs = (const float*)d_in[5];
    const float* W1 = (const float*)d_in[6];
    const float* b1 = (const float*)d_in[7];
    const float* W2 = (const float*)d_in[8];
    const float* b2 = (const float*)d_in[9];
    const float* W3 = (const float*)d_in[10];
    const float* b3 = (const float*)d_in[11];
    float* out = (float*)d_out;

    const int T = in_sizes[0];   // 128
    const int B = in_sizes[1];   // 1024
    const int D = in_sizes[4];   // 256

    node_kernel<<<B, 64, 0, stream>>>(y0, latent, length, dense_cs,
                                      W1, b1, W2, b2, W3, b3, out, T, D);
}